// Round 4
// baseline (1205.588 us; speedup 1.0000x reference)
//
#include <hip/hip_runtime.h>
#include <cstdint>
#include <cstddef>

#define N_TOKENS 16384
#define HIDDEN 1024
#define FFN 4096
#define NEXP 8
#define BM2 256                        /* GEMM tile (M and N) */
#define BK 32                         /* K step */
#define MAXR (N_TOKENS*2 + NEXP*BM2)  /* 34816 padded assignment rows */
#define MAXTILES (MAXR/BM2)           /* 136 */

typedef __bf16 bf16;
typedef __attribute__((ext_vector_type(8))) __bf16 bf16x8;
typedef __attribute__((ext_vector_type(4))) __bf16 bf16x4;
typedef __attribute__((ext_vector_type(4))) float f32x4;

__device__ __forceinline__ void gload16(const void* g, void* l) {
  __builtin_amdgcn_global_load_lds((const __attribute__((address_space(1))) void*)g,
                                   (__attribute__((address_space(3))) void*)l, 16, 0, 0);
}

// bijective XCD swizzle (m204): contiguous wg chunk per XCD
__device__ __forceinline__ int xcd_swz(int orig, int nwg) {
  int q = nwg >> 3, r = nwg & 7;
  int xcd = orig & 7, idx = orig >> 3;
  int base = (xcd < r) ? xcd * (q + 1) : r * (q + 1) + (xcd - r) * q;
  return base + idx;
}

// ---------------- conversion kernels ----------------

__global__ __launch_bounds__(256) void convx_k(const float* __restrict__ x,
                                               bf16* __restrict__ xb) {
  int i = blockIdx.x * 256 + threadIdx.x;              // over float4s
  float4 v = reinterpret_cast<const float4*>(x)[i];
  bf16x4 o = { (bf16)v.x, (bf16)v.y, (bf16)v.z, (bf16)v.w };
  *reinterpret_cast<bf16x4*>(xb + (size_t)i * 4) = o;
}

// src [z][R][C] f32 -> dst [z][C][R] bf16  (transpose + convert), 64x64 tiles
__global__ __launch_bounds__(256) void transconv_k(const float* __restrict__ src,
                                                   bf16* __restrict__ dst,
                                                   int R, int C) {
  __shared__ float tile[64][65];
  int bx = blockIdx.x * 64;   // col base (C dim)
  int by = blockIdx.y * 64;   // row base (R dim)
  const float* s = src + (size_t)blockIdx.z * R * C;
  bf16* d = dst + (size_t)blockIdx.z * R * C;
  int tid = threadIdx.x;
  int tc = (tid & 15) * 4;    // col within tile (float4)
  int tr = tid >> 4;          // 0..15
  #pragma unroll
  for (int p = 0; p < 4; ++p) {
    int r = p * 16 + tr;
    float4 v = *reinterpret_cast<const float4*>(s + (size_t)(by + r) * C + bx + tc);
    tile[r][tc] = v.x; tile[r][tc + 1] = v.y; tile[r][tc + 2] = v.z; tile[r][tc + 3] = v.w;
  }
  __syncthreads();
  int wr = (tid & 15) * 4;    // row within tile (bf16x4)
  int wc = tid >> 4;
  #pragma unroll
  for (int p = 0; p < 4; ++p) {
    int c = p * 16 + wc;
    bf16x4 o = { (bf16)tile[wr][c], (bf16)tile[wr + 1][c],
                 (bf16)tile[wr + 2][c], (bf16)tile[wr + 3][c] };
    *reinterpret_cast<bf16x4*>(d + (size_t)(bx + c) * R + by + wr) = o;
  }
}

// ---------------- router: logits (f64, one thread per token,expert) ----------------

__global__ __launch_bounds__(256) void logits_k(const float* __restrict__ x,
                                                const float* __restrict__ wrt,
                                                double* __restrict__ logitsE) {
  __shared__ float wT[NEXP][HIDDEN + 1];
  int tid = threadIdx.x;
  for (int i = tid; i < HIDDEN * NEXP; i += 256) {
    int k = i >> 3, e = i & 7;
    wT[e][k] = wrt[i];
  }
  __syncthreads();
  int t = blockIdx.x * 32 + (tid >> 3);     // token
  int e = tid & 7;                          // expert
  int goff = ((tid >> 3) & 7) * 4;          // per-group k stagger (bank spread)
  const float* xr = x + (size_t)t * HIDDEN;
  double acc = 0.0;
  #pragma unroll 4
  for (int k = 0; k < HIDDEN; k += 4) {
    int kk = (k + goff) & (HIDDEN - 1);
    float4 v = *reinterpret_cast<const float4*>(xr + kk);   // broadcast across 8 lanes
    acc += (double)v.x * (double)wT[e][kk];
    acc += (double)v.y * (double)wT[e][kk + 1];
    acc += (double)v.z * (double)wT[e][kk + 2];
    acc += (double)v.w * (double)wT[e][kk + 3];
  }
  logitsE[(size_t)e * N_TOKENS + t] = acc;
}

// ---------------- router: top-2 + weights + histogram ----------------

__global__ __launch_bounds__(256) void route_k(const double* __restrict__ logitsE,
                                               int* __restrict__ expIdx,
                                               float* __restrict__ expW,
                                               int* __restrict__ counts) {
  __shared__ int lcnt[NEXP];
  int tid = threadIdx.x;
  if (tid < NEXP) lcnt[tid] = 0;
  __syncthreads();
  int n = blockIdx.x * 256 + tid;
  double lg[NEXP];
  #pragma unroll
  for (int e = 0; e < NEXP; ++e) lg[e] = logitsE[(size_t)e * N_TOKENS + n];
  int e1 = 0;
  #pragma unroll
  for (int e = 1; e < NEXP; ++e) if (lg[e] > lg[e1]) e1 = e;
  int e2 = (e1 == 0) ? 1 : 0;
  #pragma unroll
  for (int e = 0; e < NEXP; ++e)
    if (e != e1 && e != e2 && lg[e] > lg[e2]) e2 = e;
  double d = lg[e2] - lg[e1];                                      // <= 0
  float w1v = (float)(1.0 / (1.0 + exp(d)));
  expIdx[2 * n]     = e1; expIdx[2 * n + 1] = e2;
  expW[2 * n]       = w1v; expW[2 * n + 1]  = 1.0f - w1v;
  atomicAdd(&lcnt[e1], 1);
  atomicAdd(&lcnt[e2], 1);
  __syncthreads();
  if (tid < NEXP) atomicAdd(&counts[tid], lcnt[tid]);
}

// ---------------- segment offsets + scatter ----------------

__global__ void offsets_k(const int* __restrict__ counts,
                          int* __restrict__ padOff, int* __restrict__ cursor) {
  if (threadIdx.x == 0) {
    int o = 0;
    for (int e = 0; e < NEXP; ++e) {
      padOff[e] = o;
      o += ((counts[e] + BM2 - 1) / BM2) * BM2;        // 256-aligned segments
    }
    padOff[NEXP] = o;
  }
  if (threadIdx.x < NEXP) cursor[threadIdx.x] = 0;
}

__global__ __launch_bounds__(256) void scatter_k(const int* __restrict__ expIdx,
                                                 const float* __restrict__ expW,
                                                 const int* __restrict__ padOff,
                                                 int* __restrict__ cursor,
                                                 int* __restrict__ rowTok,
                                                 float* __restrict__ rowW,
                                                 int* __restrict__ tokRow) {
  __shared__ int lcnt[NEXP], lbase[NEXP];
  int tid = threadIdx.x;
  if (tid < NEXP) lcnt[tid] = 0;
  __syncthreads();
  int n = blockIdx.x * 256 + tid;
  int e0 = expIdx[2 * n], e1 = expIdx[2 * n + 1];
  float w0 = expW[2 * n], w1 = expW[2 * n + 1];
  int p0 = atomicAdd(&lcnt[e0], 1);
  int p1 = atomicAdd(&lcnt[e1], 1);
  __syncthreads();
  if (tid < NEXP) lbase[tid] = atomicAdd(&cursor[tid], lcnt[tid]);
  __syncthreads();
  int r0 = padOff[e0] + lbase[e0] + p0;
  int r1 = padOff[e1] + lbase[e1] + p1;
  rowTok[r0] = n;  rowW[r0] = w0;  tokRow[2 * n]     = r0;
  rowTok[r1] = n;  rowW[r1] = w1;  tokRow[2 * n + 1] = r1;
}

// ---------------- deep-pipelined 256^2 grouped GEMM core ----------------
// 512 thr = 8 waves (2M x 4N); per-wave C = 128x64 = acc[8][4] 16x16 frags.
// LDS: 4-deep K-tile rotation, tile = A 256x32 + B 256x32 bf16 (16KB+16KB),
// total 128 KB. Counted vmcnt (12 = 3 tiles x 4 loads) keeps 3 tiles in
// flight across raw s_barriers; never drains to 0 in steady state (T3/T4).
// Slot swizzle: phys slot = logical ^ (row&3), applied on staging SOURCE and
// ds_read side (both-sides involution; gload_lds dest stays linear).

#define GEMM_PROLOGUE(AROWPTR_EXPR, BROW_STRIDE)                               \
  int tid = threadIdx.x;                                                       \
  int lane = tid & 63, wave = tid >> 6;                                        \
  int wm = wave >> 2, wn = wave & 3;                                           \
  int lr = lane & 15, g = lane >> 4;                                           \
  const bf16* aPtr[2]; const bf16* bPtr[2];                                    \
  int aLds[2], bLds[2];                                                        \
  _Pragma("unroll")                                                            \
  for (int j = 0; j < 2; ++j) {                                                \
    int ci = j * 512 + tid;                                                    \
    int r = ci >> 2, s = ci & 3;                                               \
    int ks = s ^ (r & 3);                                                      \
    aPtr[j] = (AROWPTR_EXPR) + ks * 8;                                         \
    bPtr[j] = Bbase + (size_t)r * (BROW_STRIDE) + ks * 8;                      \
    aLds[j] = j * 4096 + wave * 512;                                           \
    bLds[j] = j * 4096 + wave * 512;                                           \
  }                                                                            \
  int aRd = (wm * 128 + lr) * BK + ((g ^ (lr & 3)) << 3);                      \
  int bRd = (wn * 64 + lr) * BK + ((g ^ (lr & 3)) << 3);                       \
  f32x4 acc[8][4];                                                             \
  _Pragma("unroll")                                                            \
  for (int m = 0; m < 8; ++m)                                                  \
    _Pragma("unroll")                                                          \
    for (int n = 0; n < 4; ++n) acc[m][n] = (f32x4){0.f, 0.f, 0.f, 0.f};

#define STAGE(kt, b) do {                                                      \
    gload16(aPtr[0] + (size_t)(kt) * BK, &Ab[b][aLds[0]]);                     \
    gload16(aPtr[1] + (size_t)(kt) * BK, &Ab[b][aLds[1]]);                     \
    gload16(bPtr[0] + (size_t)(kt) * BK, &Bb[b][bLds[0]]);                     \
    gload16(bPtr[1] + (size_t)(kt) * BK, &Bb[b][bLds[1]]);                     \
  } while (0)

#define GEMM_KLOOP(NT)                                                         \
  STAGE(0, 0); STAGE(1, 1); STAGE(2, 2);                                       \
  _Pragma("unroll 1")                                                          \
  for (int kt = 0; kt < (NT); ++kt) {                                          \
    int b = kt & 3;                                                            \
    int pf = kt + 3;                                                           \
    if (pf < (NT)) STAGE(pf, pf & 3);                                          \
    int rem = (NT) - 1 - kt;                                                   \
    if (rem >= 3)      asm volatile("s_waitcnt vmcnt(12)" ::: "memory");       \
    else if (rem == 2) asm volatile("s_waitcnt vmcnt(8)" ::: "memory");        \
    else if (rem == 1) asm volatile("s_waitcnt vmcnt(4)" ::: "memory");        \
    else               asm volatile("s_waitcnt vmcnt(0)" ::: "memory");        \
    __builtin_amdgcn_sched_barrier(0);                                         \
    __builtin_amdgcn_s_barrier();                                              \
    __builtin_amdgcn_sched_barrier(0);                                         \
    bf16x8 af[8], bf[4];                                                       \
    _Pragma("unroll")                                                          \
    for (int m = 0; m < 8; ++m)                                                \
      af[m] = *reinterpret_cast<const bf16x8*>(&Ab[b][aRd + m * 512]);         \
    _Pragma("unroll")                                                          \
    for (int n = 0; n < 4; ++n)                                                \
      bf[n] = *reinterpret_cast<const bf16x8*>(&Bb[b][bRd + n * 512]);         \
    __builtin_amdgcn_s_setprio(1);                                             \
    _Pragma("unroll")                                                          \
    for (int m = 0; m < 8; ++m)                                                \
      _Pragma("unroll")                                                        \
      for (int n = 0; n < 4; ++n)                                              \
        acc[m][n] = __builtin_amdgcn_mfma_f32_16x16x32_bf16(af[m], bf[n],      \
                                                            acc[m][n], 0, 0, 0); \
    __builtin_amdgcn_s_setprio(0);                                             \
    __builtin_amdgcn_sched_barrier(0);                                         \
    __builtin_amdgcn_s_barrier();                                              \
    __builtin_amdgcn_sched_barrier(0);                                         \
  }

// ---------------- grouped GEMM 1: h = gelu(x_gather @ w1^T) ----------------

__device__ __forceinline__ float gelu_tanh(float v) {
  float c = 0.7978845608028654f * (v + 0.044715f * v * v * v);
  c = fminf(fmaxf(c, -15.f), 15.f);
  float ex = __expf(2.f * c);
  float t = (ex - 1.f) / (ex + 1.f);
  return 0.5f * v * (1.f + t);
}

__global__ __launch_bounds__(512, 2) void gemm1_k(const bf16* __restrict__ xb,
                                                  const bf16* __restrict__ w1bT,
                                                  bf16* __restrict__ h,
                                                  const int* __restrict__ rowTok,
                                                  const int* __restrict__ padOff,
                                                  int tileStart, int rowStart) {
  __shared__ __attribute__((aligned(16))) bf16 Ab[4][256 * BK];
  __shared__ __attribute__((aligned(16))) bf16 Bb[4][256 * BK];
  const int nCT = FFN / 256;                       // 16 col tiles
  int wg = xcd_swz((int)blockIdx.x, (int)gridDim.x);
  int bt = tileStart + wg / nCT;
  int ct = wg % nCT;
  int r0 = bt * BM2;
  if (r0 >= padOff[NEXP]) return;
  int e = 0;
  while (padOff[e + 1] <= r0) ++e;
  const bf16* Bbase = w1bT + ((size_t)e * FFN + (size_t)ct * 256) * HIDDEN;

  GEMM_PROLOGUE(xb + (size_t)(rowTok[r0 + r] < 0 ? 0 : rowTok[r0 + r]) * HIDDEN,
                HIDDEN)
  GEMM_KLOOP(HIDDEN / BK)

  int colBase = ct * 256 + wn * 64 + lr;
  #pragma unroll
  for (int m = 0; m < 8; ++m) {
    #pragma unroll
    for (int i = 0; i < 4; ++i) {
      int t = r0 + wm * 128 + m * 16 + g * 4 + i;
      bf16* hp = h + (size_t)(t - rowStart) * FFN + colBase;
      #pragma unroll
      for (int n = 0; n < 4; ++n)
        hp[n * 16] = (bf16)gelu_tanh(acc[m][n][i]);
    }
  }
}

// ---------------- grouped GEMM 2: y = h @ w2^T (bf16 y, no atomics) ----------------

__global__ __launch_bounds__(512, 2) void gemm2_k(const bf16* __restrict__ h,
                                                  const bf16* __restrict__ w2bT,
                                                  bf16* __restrict__ y,
                                                  const int* __restrict__ padOff,
                                                  int tileStart, int rowStart) {
  __shared__ __attribute__((aligned(16))) bf16 Ab[4][256 * BK];
  __shared__ __attribute__((aligned(16))) bf16 Bb[4][256 * BK];
  const int nCT = HIDDEN / 256;                    // 4 col tiles
  int wg = xcd_swz((int)blockIdx.x, (int)gridDim.x);
  int bt = tileStart + wg / nCT;
  int ct = wg % nCT;
  int r0 = bt * BM2;
  if (r0 >= padOff[NEXP]) return;
  int e = 0;
  while (padOff[e + 1] <= r0) ++e;
  const bf16* Bbase = w2bT + ((size_t)e * HIDDEN + (size_t)ct * 256) * FFN;

  GEMM_PROLOGUE(h + (size_t)(r0 - rowStart + r) * FFN, FFN)
  GEMM_KLOOP(FFN / BK)

  int colBase = ct * 256 + wn * 64 + lr;
  #pragma unroll
  for (int m = 0; m < 8; ++m) {
    #pragma unroll
    for (int i = 0; i < 4; ++i) {
      int t = r0 + wm * 128 + m * 16 + g * 4 + i;
      bf16* yp = y + (size_t)t * HIDDEN + colBase;
      #pragma unroll
      for (int n = 0; n < 4; ++n)
        yp[n * 16] = (bf16)acc[m][n][i];
    }
  }
}

// ---------------- combine: out[n] = w0*y[r0] + w1*y[r1] ----------------

__global__ __launch_bounds__(256) void combine_k(const bf16* __restrict__ y,
                                                 const int* __restrict__ tokRow,
                                                 const float* __restrict__ rowW,
                                                 float* __restrict__ out) {
  int n = blockIdx.x;
  int c = threadIdx.x * 4;
  int r0 = tokRow[2 * n], r1 = tokRow[2 * n + 1];
  float w0 = rowW[r0], w1 = rowW[r1];
  bf16x4 a = *reinterpret_cast<const bf16x4*>(y + (size_t)r0 * HIDDEN + c);
  bf16x4 b = *reinterpret_cast<const bf16x4*>(y + (size_t)r1 * HIDDEN + c);
  float4 o = { w0 * (float)a[0] + w1 * (float)b[0], w0 * (float)a[1] + w1 * (float)b[1],
               w0 * (float)a[2] + w1 * (float)b[2], w0 * (float)a[3] + w1 * (float)b[3] };
  *reinterpret_cast<float4*>(out + (size_t)n * HIDDEN + c) = o;
}

// ---------------- host ----------------

extern "C" void kernel_launch(void* const* d_in, const int* in_sizes, int n_in,
                              void* d_out, int out_size, void* d_ws, size_t ws_size,
                              hipStream_t stream) {
  const float* x   = (const float*)d_in[0];
  const float* wrt = (const float*)d_in[1];
  const float* w1  = (const float*)d_in[2];
  const float* w2  = (const float*)d_in[3];
  float* out = (float*)d_out;

  char* p = (char*)d_ws;
  size_t off = 0;
  auto alloc = [&](size_t bytes) -> void* {
    void* r = p + off;
    off = (off + bytes + 255) & ~(size_t)255;
    return r;
  };

  int*    counts  = (int*)   alloc(NEXP * 4);
  int*    padOff  = (int*)   alloc((NEXP + 1) * 4);
  int*    cursor  = (int*)   alloc(NEXP * 4);
  int*    expIdx  = (int*)   alloc((size_t)N_TOKENS * 2 * 4);
  float*  expW    = (float*) alloc((size_t)N_TOKENS * 2 * 4);
  int*    rowTok  = (int*)   alloc((size_t)MAXR * 4);
  float*  rowW    = (float*) alloc((size_t)MAXR * 4);
  int*    tokRow  = (int*)   alloc((size_t)N_TOKENS * 2 * 4);
  double* logitsE = (double*)alloc((size_t)NEXP * N_TOKENS * 8);
  bf16*   xb      = (bf16*)  alloc((size_t)N_TOKENS * HIDDEN * 2);
  bf16*   w1bT    = (bf16*)  alloc((size_t)NEXP * FFN * HIDDEN * 2);
  bf16*   w2bT    = (bf16*)  alloc((size_t)NEXP * FFN * HIDDEN * 2);
  bf16*   y       = (bf16*)  alloc((size_t)MAXR * HIDDEN * 2);
  size_t fixed = off;
  bf16* h = (bf16*)(p + fixed);

  size_t tileB = (size_t)BM2 * FFN * 2;            // 2 MiB per 256-row tile of h
  size_t avail = (ws_size > fixed) ? (ws_size - fixed) : tileB;
  size_t fitSz = avail / tileB;
  int tilesFit = (int)((fitSz < (size_t)MAXTILES) ? fitSz : (size_t)MAXTILES);
  if (tilesFit < 1) tilesFit = 1;
  int nchunks = (MAXTILES + tilesFit - 1) / tilesFit;
  int tpc = (MAXTILES + nchunks - 1) / nchunks;

  hipMemsetAsync(counts, 0, NEXP * 4, stream);
  hipMemsetAsync(rowTok, 0xFF, (size_t)MAXR * 4, stream);

  convx_k<<<N_TOKENS * HIDDEN / 4 / 256, 256, 0, stream>>>(x, xb);
  transconv_k<<<dim3(FFN / 64, HIDDEN / 64, NEXP), dim3(256, 1, 1), 0, stream>>>(w1, w1bT, HIDDEN, FFN);
  transconv_k<<<dim3(HIDDEN / 64, FFN / 64, NEXP), dim3(256, 1, 1), 0, stream>>>(w2, w2bT, FFN, HIDDEN);
  logits_k<<<N_TOKENS / 32, 256, 0, stream>>>(x, wrt, logitsE);
  route_k<<<N_TOKENS / 256, 256, 0, stream>>>(logitsE, expIdx, expW, counts);
  offsets_k<<<1, 64, 0, stream>>>(counts, padOff, cursor);
  scatter_k<<<N_TOKENS / 256, 256, 0, stream>>>(expIdx, expW, padOff, cursor, rowTok, rowW, tokRow);

  for (int c = 0; c < nchunks; ++c) {
    int ts = c * tpc;
    int rs = ts * BM2;
    gemm1_k<<<tpc * (FFN / 256), 512, 0, stream>>>(xb, w1bT, h, rowTok, padOff, ts, rs);
    gemm2_k<<<tpc * (HIDDEN / 256), 512, 0, stream>>>(h, w2bT, y, padOff, ts, rs);
  }
  combine_k<<<N_TOKENS, 256, 0, stream>>>(y, tokRow, rowW, out);
}

// Round 5
// 1043.707 us; speedup vs baseline: 1.1551x; 1.1551x over previous
//
#include <hip/hip_runtime.h>
#include <cstdint>
#include <cstddef>

#define N_TOKENS 16384
#define HIDDEN 1024
#define FFN 4096
#define NEXP 8
#define BM2 256                        /* GEMM tile (M and N) */
#define BK 64                          /* K step */
#define MAXR (N_TOKENS*2 + NEXP*BM2)  /* 34816 padded assignment rows */
#define MAXTILES (MAXR/BM2)           /* 136 */

typedef __bf16 bf16;
typedef __attribute__((ext_vector_type(8))) __bf16 bf16x8;
typedef __attribute__((ext_vector_type(4))) __bf16 bf16x4;
typedef __attribute__((ext_vector_type(4))) float f32x4;

__device__ __forceinline__ void gload16(const void* g, void* l) {
  __builtin_amdgcn_global_load_lds((const __attribute__((address_space(1))) void*)g,
                                   (__attribute__((address_space(3))) void*)l, 16, 0, 0);
}

// bijective XCD swizzle (m204): contiguous wg chunk per XCD
__device__ __forceinline__ int xcd_swz(int orig, int nwg) {
  int q = nwg >> 3, r = nwg & 7;
  int xcd = orig & 7, idx = orig >> 3;
  int base = (xcd < r) ? xcd * (q + 1) : r * (q + 1) + (xcd - r) * q;
  return base + idx;
}

// ---------------- conversion kernels ----------------

__global__ __launch_bounds__(256) void convx_k(const float* __restrict__ x,
                                               bf16* __restrict__ xb) {
  int i = blockIdx.x * 256 + threadIdx.x;              // over float4s
  float4 v = reinterpret_cast<const float4*>(x)[i];
  bf16x4 o = { (bf16)v.x, (bf16)v.y, (bf16)v.z, (bf16)v.w };
  *reinterpret_cast<bf16x4*>(xb + (size_t)i * 4) = o;
}

// src [z][R][C] f32 -> dst [z][C][R] bf16  (transpose + convert), 64x64 tiles
__global__ __launch_bounds__(256) void transconv_k(const float* __restrict__ src,
                                                   bf16* __restrict__ dst,
                                                   int R, int C) {
  __shared__ float tile[64][65];
  int bx = blockIdx.x * 64;   // col base (C dim)
  int by = blockIdx.y * 64;   // row base (R dim)
  const float* s = src + (size_t)blockIdx.z * R * C;
  bf16* d = dst + (size_t)blockIdx.z * R * C;
  int tid = threadIdx.x;
  int tc = (tid & 15) * 4;    // col within tile (float4)
  int tr = tid >> 4;          // 0..15
  #pragma unroll
  for (int p = 0; p < 4; ++p) {
    int r = p * 16 + tr;
    float4 v = *reinterpret_cast<const float4*>(s + (size_t)(by + r) * C + bx + tc);
    tile[r][tc] = v.x; tile[r][tc + 1] = v.y; tile[r][tc + 2] = v.z; tile[r][tc + 3] = v.w;
  }
  __syncthreads();
  int wr = (tid & 15) * 4;    // row within tile (bf16x4)
  int wc = tid >> 4;
  #pragma unroll
  for (int p = 0; p < 4; ++p) {
    int c = p * 16 + wc;
    bf16x4 o = { (bf16)tile[wr][c], (bf16)tile[wr + 1][c],
                 (bf16)tile[wr + 2][c], (bf16)tile[wr + 3][c] };
    *reinterpret_cast<bf16x4*>(d + (size_t)(bx + c) * R + by + wr) = o;
  }
}

// ---------------- router: logits (f64, one thread per token,expert) ----------------

__global__ __launch_bounds__(256) void logits_k(const float* __restrict__ x,
                                                const float* __restrict__ wrt,
                                                double* __restrict__ logitsE) {
  __shared__ float wT[NEXP][HIDDEN + 1];
  int tid = threadIdx.x;
  for (int i = tid; i < HIDDEN * NEXP; i += 256) {
    int k = i >> 3, e = i & 7;
    wT[e][k] = wrt[i];
  }
  __syncthreads();
  int t = blockIdx.x * 32 + (tid >> 3);     // token
  int e = tid & 7;                          // expert
  int goff = ((tid >> 3) & 7) * 4;          // per-group k stagger (bank spread)
  const float* xr = x + (size_t)t * HIDDEN;
  double acc = 0.0;
  #pragma unroll 4
  for (int k = 0; k < HIDDEN; k += 4) {
    int kk = (k + goff) & (HIDDEN - 1);
    float4 v = *reinterpret_cast<const float4*>(xr + kk);   // broadcast across 8 lanes
    acc += (double)v.x * (double)wT[e][kk];
    acc += (double)v.y * (double)wT[e][kk + 1];
    acc += (double)v.z * (double)wT[e][kk + 2];
    acc += (double)v.w * (double)wT[e][kk + 3];
  }
  logitsE[(size_t)e * N_TOKENS + t] = acc;
}

// ---------------- router: top-2 + weights + histogram ----------------

__global__ __launch_bounds__(256) void route_k(const double* __restrict__ logitsE,
                                               int* __restrict__ expIdx,
                                               float* __restrict__ expW,
                                               int* __restrict__ counts) {
  __shared__ int lcnt[NEXP];
  int tid = threadIdx.x;
  if (tid < NEXP) lcnt[tid] = 0;
  __syncthreads();
  int n = blockIdx.x * 256 + tid;
  double lg[NEXP];
  #pragma unroll
  for (int e = 0; e < NEXP; ++e) lg[e] = logitsE[(size_t)e * N_TOKENS + n];
  int e1 = 0;
  #pragma unroll
  for (int e = 1; e < NEXP; ++e) if (lg[e] > lg[e1]) e1 = e;
  int e2 = (e1 == 0) ? 1 : 0;
  #pragma unroll
  for (int e = 0; e < NEXP; ++e)
    if (e != e1 && e != e2 && lg[e] > lg[e2]) e2 = e;
  double d = lg[e2] - lg[e1];                                      // <= 0
  float w1v = (float)(1.0 / (1.0 + exp(d)));
  expIdx[2 * n]     = e1; expIdx[2 * n + 1] = e2;
  expW[2 * n]       = w1v; expW[2 * n + 1]  = 1.0f - w1v;
  atomicAdd(&lcnt[e1], 1);
  atomicAdd(&lcnt[e2], 1);
  __syncthreads();
  if (tid < NEXP) atomicAdd(&counts[tid], lcnt[tid]);
}

// ---------------- segment offsets + scatter ----------------

__global__ void offsets_k(const int* __restrict__ counts,
                          int* __restrict__ padOff, int* __restrict__ cursor) {
  if (threadIdx.x == 0) {
    int o = 0;
    for (int e = 0; e < NEXP; ++e) {
      padOff[e] = o;
      o += ((counts[e] + BM2 - 1) / BM2) * BM2;        // 256-aligned segments
    }
    padOff[NEXP] = o;
  }
  if (threadIdx.x < NEXP) cursor[threadIdx.x] = 0;
}

__global__ __launch_bounds__(256) void scatter_k(const int* __restrict__ expIdx,
                                                 const float* __restrict__ expW,
                                                 const int* __restrict__ padOff,
                                                 int* __restrict__ cursor,
                                                 int* __restrict__ rowTok,
                                                 float* __restrict__ rowW,
                                                 int* __restrict__ tokRow) {
  __shared__ int lcnt[NEXP], lbase[NEXP];
  int tid = threadIdx.x;
  if (tid < NEXP) lcnt[tid] = 0;
  __syncthreads();
  int n = blockIdx.x * 256 + tid;
  int e0 = expIdx[2 * n], e1 = expIdx[2 * n + 1];
  float w0 = expW[2 * n], w1 = expW[2 * n + 1];
  int p0 = atomicAdd(&lcnt[e0], 1);
  int p1 = atomicAdd(&lcnt[e1], 1);
  __syncthreads();
  if (tid < NEXP) lbase[tid] = atomicAdd(&cursor[tid], lcnt[tid]);
  __syncthreads();
  int r0 = padOff[e0] + lbase[e0] + p0;
  int r1 = padOff[e1] + lbase[e1] + p1;
  rowTok[r0] = n;  rowW[r0] = w0;  tokRow[2 * n]     = r0;
  rowTok[r1] = n;  rowW[r1] = w1;  tokRow[2 * n + 1] = r1;
}

// ---------------- 256^2 grouped GEMM core, BK=64, depth-2 ----------------
// 512 thr = 8 waves (2M x 4N); per-wave C = 128x64 = acc[8][4] 16x16 frags.
// LDS: 2 buffers, each A[256][64]+B[256][64] bf16 = 64 KB -> 128 KB total.
// Schedule per iter kt (buf b = kt&1):
//   vmcnt(8)  -> tile kt landed (issued 2 iters ago; tile kt+1's 8 stay in flight)
//   barrier   -> cross-wave visibility of tile kt
//   ds_read + 2x32 MFMA (kk halves; compiler pipelines lgkmcnt)
//   barrier   -> all waves done reading buf b
//   STAGE(kt+2 -> buf b)   (issue only, no wait)
// Swizzle (row stride 128 B = 32 banks): phys16Bslot = slot ^ (row&7), applied
// to the staging SOURCE k-offset and the ds_read address (rows == lr mod 8 ->
// 8 distinct bank-groups per 8-lane phase, conflict-free).

#define GEMM_PROLOGUE(AROWPTR_EXPR, BROW_STRIDE)                               \
  int tid = threadIdx.x;                                                       \
  int lane = tid & 63, wave = tid >> 6;                                        \
  int wm = wave >> 2, wn = wave & 3;                                           \
  int lr = lane & 15, g = lane >> 4;                                           \
  const bf16* aPtr[4]; const bf16* bPtr[4]; int aLds[4];                       \
  _Pragma("unroll")                                                            \
  for (int j = 0; j < 4; ++j) {                                                \
    int ci = j * 512 + tid;                                                    \
    int r = ci >> 3, s = ci & 7;                                               \
    int ks = s ^ (r & 7);                                                      \
    aPtr[j] = (AROWPTR_EXPR) + ks * 8;                                         \
    bPtr[j] = Bbase + (size_t)r * (BROW_STRIDE) + ks * 8;                      \
    aLds[j] = j * 4096 + wave * 512;                                           \
  }                                                                            \
  int rowA = wm * 128 + lr, rowB = wn * 64 + lr;                               \
  int aRd0 = rowA * BK + ((g ^ (lr & 7)) << 3);                                \
  int aRd1 = rowA * BK + (((4 + g) ^ (lr & 7)) << 3);                          \
  int bRd0 = rowB * BK + ((g ^ (lr & 7)) << 3);                                \
  int bRd1 = rowB * BK + (((4 + g) ^ (lr & 7)) << 3);                          \
  f32x4 acc[8][4];                                                             \
  _Pragma("unroll")                                                            \
  for (int m = 0; m < 8; ++m)                                                  \
    _Pragma("unroll")                                                          \
    for (int n = 0; n < 4; ++n) acc[m][n] = (f32x4){0.f, 0.f, 0.f, 0.f};

#define STAGE(kt, b) do {                                                      \
    _Pragma("unroll")                                                          \
    for (int j = 0; j < 4; ++j)                                                \
      gload16(aPtr[j] + (size_t)(kt) * BK, &Ab[b][aLds[j]]);                   \
    _Pragma("unroll")                                                          \
    for (int j = 0; j < 4; ++j)                                                \
      gload16(bPtr[j] + (size_t)(kt) * BK, &Bb[b][aLds[j]]);                   \
  } while (0)

#define HALF_COMPUTE(b, ARD, BRD)                                              \
  {                                                                            \
    bf16x8 af[8], bfr[4];                                                      \
    _Pragma("unroll")                                                          \
    for (int m = 0; m < 8; ++m)                                                \
      af[m] = *reinterpret_cast<const bf16x8*>(&Ab[b][(ARD) + m * 1024]);      \
    _Pragma("unroll")                                                          \
    for (int n = 0; n < 4; ++n)                                                \
      bfr[n] = *reinterpret_cast<const bf16x8*>(&Bb[b][(BRD) + n * 1024]);     \
    __builtin_amdgcn_s_setprio(1);                                             \
    _Pragma("unroll")                                                          \
    for (int m = 0; m < 8; ++m)                                                \
      _Pragma("unroll")                                                        \
      for (int n = 0; n < 4; ++n)                                              \
        acc[m][n] = __builtin_amdgcn_mfma_f32_16x16x32_bf16(af[m], bfr[n],     \
                                                            acc[m][n], 0, 0, 0); \
    __builtin_amdgcn_s_setprio(0);                                             \
  }

#define GEMM_KLOOP(NT)                                                         \
  STAGE(0, 0);                                                                 \
  STAGE(1, 1);                                                                 \
  _Pragma("unroll 1")                                                          \
  for (int kt = 0; kt < (NT); ++kt) {                                          \
    int b = kt & 1;                                                            \
    if (kt < (NT) - 1) asm volatile("s_waitcnt vmcnt(8)" ::: "memory");        \
    else               asm volatile("s_waitcnt vmcnt(0)" ::: "memory");        \
    __builtin_amdgcn_sched_barrier(0);                                         \
    __builtin_amdgcn_s_barrier();                                              \
    __builtin_amdgcn_sched_barrier(0);                                         \
    HALF_COMPUTE(b, aRd0, bRd0)                                                \
    HALF_COMPUTE(b, aRd1, bRd1)                                                \
    __builtin_amdgcn_sched_barrier(0);                                         \
    __builtin_amdgcn_s_barrier();                                              \
    __builtin_amdgcn_sched_barrier(0);                                         \
    if (kt + 2 < (NT)) STAGE(kt + 2, b);                                       \
  }

// ---------------- grouped GEMM 1: h = gelu(x_gather @ w1^T) ----------------

__device__ __forceinline__ float gelu_tanh(float v) {
  float c = 0.7978845608028654f * (v + 0.044715f * v * v * v);
  c = fminf(fmaxf(c, -15.f), 15.f);
  float ex = __expf(2.f * c);
  float t = (ex - 1.f) / (ex + 1.f);
  return 0.5f * v * (1.f + t);
}

__global__ __launch_bounds__(512, 2) void gemm1_k(const bf16* __restrict__ xb,
                                                  const bf16* __restrict__ w1bT,
                                                  bf16* __restrict__ h,
                                                  const int* __restrict__ rowTok,
                                                  const int* __restrict__ padOff,
                                                  int tileStart, int rowStart) {
  __shared__ __attribute__((aligned(16))) bf16 Ab[2][256 * BK];
  __shared__ __attribute__((aligned(16))) bf16 Bb[2][256 * BK];
  const int nCT = FFN / 256;                       // 16 col tiles
  int wg = xcd_swz((int)blockIdx.x, (int)gridDim.x);
  int bt = tileStart + wg / nCT;
  int ct = wg % nCT;
  int r0 = bt * BM2;
  if (r0 >= padOff[NEXP]) return;
  int e = 0;
  while (padOff[e + 1] <= r0) ++e;
  const bf16* Bbase = w1bT + ((size_t)e * FFN + (size_t)ct * 256) * HIDDEN;

  GEMM_PROLOGUE(xb + (size_t)(rowTok[r0 + r] < 0 ? 0 : rowTok[r0 + r]) * HIDDEN,
                HIDDEN)
  GEMM_KLOOP(HIDDEN / BK)

  int colBase = ct * 256 + wn * 64 + lr;
  #pragma unroll
  for (int m = 0; m < 8; ++m) {
    #pragma unroll
    for (int i = 0; i < 4; ++i) {
      int t = r0 + wm * 128 + m * 16 + g * 4 + i;
      bf16* hp = h + (size_t)(t - rowStart) * FFN + colBase;
      #pragma unroll
      for (int n = 0; n < 4; ++n)
        hp[n * 16] = (bf16)gelu_tanh(acc[m][n][i]);
    }
  }
}

// ---------------- grouped GEMM 2: y = h @ w2^T (bf16 y, no atomics) ----------------

__global__ __launch_bounds__(512, 2) void gemm2_k(const bf16* __restrict__ h,
                                                  const bf16* __restrict__ w2bT,
                                                  bf16* __restrict__ y,
                                                  const int* __restrict__ padOff,
                                                  int tileStart, int rowStart) {
  __shared__ __attribute__((aligned(16))) bf16 Ab[2][256 * BK];
  __shared__ __attribute__((aligned(16))) bf16 Bb[2][256 * BK];
  const int nCT = HIDDEN / 256;                    // 4 col tiles
  int wg = xcd_swz((int)blockIdx.x, (int)gridDim.x);
  int bt = tileStart + wg / nCT;
  int ct = wg % nCT;
  int r0 = bt * BM2;
  if (r0 >= padOff[NEXP]) return;
  int e = 0;
  while (padOff[e + 1] <= r0) ++e;
  const bf16* Bbase = w2bT + ((size_t)e * HIDDEN + (size_t)ct * 256) * FFN;

  GEMM_PROLOGUE(h + (size_t)(r0 - rowStart + r) * FFN, FFN)
  GEMM_KLOOP(FFN / BK)

  int colBase = ct * 256 + wn * 64 + lr;
  #pragma unroll
  for (int m = 0; m < 8; ++m) {
    #pragma unroll
    for (int i = 0; i < 4; ++i) {
      int t = r0 + wm * 128 + m * 16 + g * 4 + i;
      bf16* yp = y + (size_t)t * HIDDEN + colBase;
      #pragma unroll
      for (int n = 0; n < 4; ++n)
        yp[n * 16] = (bf16)acc[m][n][i];
    }
  }
}

// ---------------- combine: out[n] = w0*y[r0] + w1*y[r1] ----------------

__global__ __launch_bounds__(256) void combine_k(const bf16* __restrict__ y,
                                                 const int* __restrict__ tokRow,
                                                 const float* __restrict__ rowW,
                                                 float* __restrict__ out) {
  int n = blockIdx.x;
  int c = threadIdx.x * 4;
  int r0 = tokRow[2 * n], r1 = tokRow[2 * n + 1];
  float w0 = rowW[r0], w1 = rowW[r1];
  bf16x4 a = *reinterpret_cast<const bf16x4*>(y + (size_t)r0 * HIDDEN + c);
  bf16x4 b = *reinterpret_cast<const bf16x4*>(y + (size_t)r1 * HIDDEN + c);
  float4 o = { w0 * (float)a[0] + w1 * (float)b[0], w0 * (float)a[1] + w1 * (float)b[1],
               w0 * (float)a[2] + w1 * (float)b[2], w0 * (float)a[3] + w1 * (float)b[3] };
  *reinterpret_cast<float4*>(out + (size_t)n * HIDDEN + c) = o;
}

// ---------------- host ----------------

extern "C" void kernel_launch(void* const* d_in, const int* in_sizes, int n_in,
                              void* d_out, int out_size, void* d_ws, size_t ws_size,
                              hipStream_t stream) {
  const float* x   = (const float*)d_in[0];
  const float* wrt = (const float*)d_in[1];
  const float* w1  = (const float*)d_in[2];
  const float* w2  = (const float*)d_in[3];
  float* out = (float*)d_out;

  char* p = (char*)d_ws;
  size_t off = 0;
  auto alloc = [&](size_t bytes) -> void* {
    void* r = p + off;
    off = (off + bytes + 255) & ~(size_t)255;
    return r;
  };

  int*    counts  = (int*)   alloc(NEXP * 4);
  int*    padOff  = (int*)   alloc((NEXP + 1) * 4);
  int*    cursor  = (int*)   alloc(NEXP * 4);
  int*    expIdx  = (int*)   alloc((size_t)N_TOKENS * 2 * 4);
  float*  expW    = (float*) alloc((size_t)N_TOKENS * 2 * 4);
  int*    rowTok  = (int*)   alloc((size_t)MAXR * 4);
  float*  rowW    = (float*) alloc((size_t)MAXR * 4);
  int*    tokRow  = (int*)   alloc((size_t)N_TOKENS * 2 * 4);
  double* logitsE = (double*)alloc((size_t)NEXP * N_TOKENS * 8);
  bf16*   xb      = (bf16*)  alloc((size_t)N_TOKENS * HIDDEN * 2);
  bf16*   w1bT    = (bf16*)  alloc((size_t)NEXP * FFN * HIDDEN * 2);
  bf16*   w2bT    = (bf16*)  alloc((size_t)NEXP * FFN * HIDDEN * 2);
  bf16*   y       = (bf16*)  alloc((size_t)MAXR * HIDDEN * 2);
  size_t fixed = off;
  bf16* h = (bf16*)(p + fixed);

  size_t tileB = (size_t)BM2 * FFN * 2;            // 2 MiB per 256-row tile of h
  size_t avail = (ws_size > fixed) ? (ws_size - fixed) : tileB;
  size_t fitSz = avail / tileB;
  int tilesFit = (int)((fitSz < (size_t)MAXTILES) ? fitSz : (size_t)MAXTILES);
  if (tilesFit < 1) tilesFit = 1;
  int nchunks = (MAXTILES + tilesFit - 1) / tilesFit;
  int tpc = (MAXTILES + nchunks - 1) / nchunks;

  hipMemsetAsync(counts, 0, NEXP * 4, stream);
  hipMemsetAsync(rowTok, 0xFF, (size_t)MAXR * 4, stream);

  convx_k<<<N_TOKENS * HIDDEN / 4 / 256, 256, 0, stream>>>(x, xb);
  transconv_k<<<dim3(FFN / 64, HIDDEN / 64, NEXP), dim3(256, 1, 1), 0, stream>>>(w1, w1bT, HIDDEN, FFN);
  transconv_k<<<dim3(HIDDEN / 64, FFN / 64, NEXP), dim3(256, 1, 1), 0, stream>>>(w2, w2bT, FFN, HIDDEN);
  logits_k<<<N_TOKENS / 32, 256, 0, stream>>>(x, wrt, logitsE);
  route_k<<<N_TOKENS / 256, 256, 0, stream>>>(logitsE, expIdx, expW, counts);
  offsets_k<<<1, 64, 0, stream>>>(counts, padOff, cursor);
  scatter_k<<<N_TOKENS / 256, 256, 0, stream>>>(expIdx, expW, padOff, cursor, rowTok, rowW, tokRow);

  for (int c = 0; c < nchunks; ++c) {
    int ts = c * tpc;
    int rs = ts * BM2;
    gemm1_k<<<tpc * (FFN / 256), 512, 0, stream>>>(xb, w1bT, h, rowTok, padOff, ts, rs);
    gemm2_k<<<tpc * (HIDDEN / 256), 512, 0, stream>>>(h, w2bT, y, padOff, ts, rs);
  }
  combine_k<<<N_TOKENS, 256, 0, stream>>>(y, tokRow, rowW, out);
}

// Round 6
// 1024.354 us; speedup vs baseline: 1.1769x; 1.0189x over previous
//
#include <hip/hip_runtime.h>
#include <cstdint>
#include <cstddef>

#define N_TOKENS 16384
#define HIDDEN 1024
#define FFN 4096
#define NEXP 8
#define BM2 256                        /* GEMM tile (M and N) */
#define MAXR (N_TOKENS*2 + NEXP*BM2)  /* 34816 padded assignment rows */
#define MAXTILES (MAXR/BM2)           /* 136 */

typedef __bf16 bf16;
typedef __attribute__((ext_vector_type(8))) __bf16 bf16x8;
typedef __attribute__((ext_vector_type(4))) __bf16 bf16x4;
typedef __attribute__((ext_vector_type(4))) float f32x4;

__device__ __forceinline__ void gload16(const void* g, void* l) {
  __builtin_amdgcn_global_load_lds((const __attribute__((address_space(1))) void*)g,
                                   (__attribute__((address_space(3))) void*)l, 16, 0, 0);
}

// bijective XCD swizzle (m204): contiguous wg chunk per XCD
__device__ __forceinline__ int xcd_swz(int orig, int nwg) {
  int q = nwg >> 3, r = nwg & 7;
  int xcd = orig & 7, idx = orig >> 3;
  int base = (xcd < r) ? xcd * (q + 1) : r * (q + 1) + (xcd - r) * q;
  return base + idx;
}

// ---------------- conversion kernels ----------------

__global__ __launch_bounds__(256) void convx_k(const float* __restrict__ x,
                                               bf16* __restrict__ xb) {
  int i = blockIdx.x * 256 + threadIdx.x;              // over float4s
  float4 v = reinterpret_cast<const float4*>(x)[i];
  bf16x4 o = { (bf16)v.x, (bf16)v.y, (bf16)v.z, (bf16)v.w };
  *reinterpret_cast<bf16x4*>(xb + (size_t)i * 4) = o;
}

// src [z][R][C] f32 -> dst [z][C][R] bf16  (transpose + convert), 64x64 tiles
__global__ __launch_bounds__(256) void transconv_k(const float* __restrict__ src,
                                                   bf16* __restrict__ dst,
                                                   int R, int C) {
  __shared__ float tile[64][65];
  int bx = blockIdx.x * 64;   // col base (C dim)
  int by = blockIdx.y * 64;   // row base (R dim)
  const float* s = src + (size_t)blockIdx.z * R * C;
  bf16* d = dst + (size_t)blockIdx.z * R * C;
  int tid = threadIdx.x;
  int tc = (tid & 15) * 4;    // col within tile (float4)
  int tr = tid >> 4;          // 0..15
  #pragma unroll
  for (int p = 0; p < 4; ++p) {
    int r = p * 16 + tr;
    float4 v = *reinterpret_cast<const float4*>(s + (size_t)(by + r) * C + bx + tc);
    tile[r][tc] = v.x; tile[r][tc + 1] = v.y; tile[r][tc + 2] = v.z; tile[r][tc + 3] = v.w;
  }
  __syncthreads();
  int wr = (tid & 15) * 4;    // row within tile (bf16x4)
  int wc = tid >> 4;
  #pragma unroll
  for (int p = 0; p < 4; ++p) {
    int c = p * 16 + wc;
    bf16x4 o = { (bf16)tile[wr][c], (bf16)tile[wr + 1][c],
                 (bf16)tile[wr + 2][c], (bf16)tile[wr + 3][c] };
    *reinterpret_cast<bf16x4*>(d + (size_t)(bx + c) * R + by + wr) = o;
  }
}

// ---------------- router: logits (f64, one thread per token,expert) ----------------

__global__ __launch_bounds__(256) void logits_k(const float* __restrict__ x,
                                                const float* __restrict__ wrt,
                                                double* __restrict__ logitsE) {
  __shared__ float wT[NEXP][HIDDEN + 1];
  int tid = threadIdx.x;
  for (int i = tid; i < HIDDEN * NEXP; i += 256) {
    int k = i >> 3, e = i & 7;
    wT[e][k] = wrt[i];
  }
  __syncthreads();
  int t = blockIdx.x * 32 + (tid >> 3);     // token
  int e = tid & 7;                          // expert
  int goff = ((tid >> 3) & 7) * 4;          // per-group k stagger (bank spread)
  const float* xr = x + (size_t)t * HIDDEN;
  double acc = 0.0;
  #pragma unroll 4
  for (int k = 0; k < HIDDEN; k += 4) {
    int kk = (k + goff) & (HIDDEN - 1);
    float4 v = *reinterpret_cast<const float4*>(xr + kk);   // broadcast across 8 lanes
    acc += (double)v.x * (double)wT[e][kk];
    acc += (double)v.y * (double)wT[e][kk + 1];
    acc += (double)v.z * (double)wT[e][kk + 2];
    acc += (double)v.w * (double)wT[e][kk + 3];
  }
  logitsE[(size_t)e * N_TOKENS + t] = acc;
}

// ---------------- router: top-2 + weights + histogram ----------------

__global__ __launch_bounds__(256) void route_k(const double* __restrict__ logitsE,
                                               int* __restrict__ expIdx,
                                               float* __restrict__ expW,
                                               int* __restrict__ counts) {
  __shared__ int lcnt[NEXP];
  int tid = threadIdx.x;
  if (tid < NEXP) lcnt[tid] = 0;
  __syncthreads();
  int n = blockIdx.x * 256 + tid;
  double lg[NEXP];
  #pragma unroll
  for (int e = 0; e < NEXP; ++e) lg[e] = logitsE[(size_t)e * N_TOKENS + n];
  int e1 = 0;
  #pragma unroll
  for (int e = 1; e < NEXP; ++e) if (lg[e] > lg[e1]) e1 = e;
  int e2 = (e1 == 0) ? 1 : 0;
  #pragma unroll
  for (int e = 0; e < NEXP; ++e)
    if (e != e1 && e != e2 && lg[e] > lg[e2]) e2 = e;
  double d = lg[e2] - lg[e1];                                      // <= 0
  float w1v = (float)(1.0 / (1.0 + exp(d)));
  expIdx[2 * n]     = e1; expIdx[2 * n + 1] = e2;
  expW[2 * n]       = w1v; expW[2 * n + 1]  = 1.0f - w1v;
  atomicAdd(&lcnt[e1], 1);
  atomicAdd(&lcnt[e2], 1);
  __syncthreads();
  if (tid < NEXP) atomicAdd(&counts[tid], lcnt[tid]);
}

// ---------------- segment offsets + scatter ----------------

__global__ void offsets_k(const int* __restrict__ counts,
                          int* __restrict__ padOff, int* __restrict__ cursor) {
  if (threadIdx.x == 0) {
    int o = 0;
    for (int e = 0; e < NEXP; ++e) {
      padOff[e] = o;
      o += ((counts[e] + BM2 - 1) / BM2) * BM2;        // 256-aligned segments
    }
    padOff[NEXP] = o;
  }
  if (threadIdx.x < NEXP) cursor[threadIdx.x] = 0;
}

__global__ __launch_bounds__(256) void scatter_k(const int* __restrict__ expIdx,
                                                 const float* __restrict__ expW,
                                                 const int* __restrict__ padOff,
                                                 int* __restrict__ cursor,
                                                 int* __restrict__ rowTok,
                                                 float* __restrict__ rowW,
                                                 int* __restrict__ tokRow) {
  __shared__ int lcnt[NEXP], lbase[NEXP];
  int tid = threadIdx.x;
  if (tid < NEXP) lcnt[tid] = 0;
  __syncthreads();
  int n = blockIdx.x * 256 + tid;
  int e0 = expIdx[2 * n], e1 = expIdx[2 * n + 1];
  float w0 = expW[2 * n], w1 = expW[2 * n + 1];
  int p0 = atomicAdd(&lcnt[e0], 1);
  int p1 = atomicAdd(&lcnt[e1], 1);
  __syncthreads();
  if (tid < NEXP) lbase[tid] = atomicAdd(&cursor[tid], lcnt[tid]);
  __syncthreads();
  int r0 = padOff[e0] + lbase[e0] + p0;
  int r1 = padOff[e1] + lbase[e1] + p1;
  rowTok[r0] = n;  rowW[r0] = w0;  tokRow[2 * n]     = r0;
  rowTok[r1] = n;  rowW[r1] = w1;  tokRow[2 * n + 1] = r1;
}

// ---------------- 256^2 grouped GEMM core: 32-K slots, depth-4, 2-phase ----------------
// 512 thr = 8 waves (2M x 4N); per-wave C = 128x64 = acc[8][4] 16x16 frags.
// LDS: 4 slot-buffers per operand, slot = 256 rows x 32 k bf16 (16 KB) -> 128 KB.
// Per slot s (buf s&3), two phases, each:
//   {ds_read 4-8 x b128 | 2 x global_load_lds (slot s+3) | s_barrier |
//    lgkmcnt(0)+sched_barrier | setprio(1) 16 MFMA setprio(0) | s_barrier}
// Counted vmcnt once per slot in P1 (retires slot s+1; slots s+2,s+3 stay in
// flight -> never drains in steady state). Prologue stages slots 0..2.
// Race safety: gloads of slot s+3 hit buf (s-1)&3; all reads of that buf were
// lgkm-drained before each wave's last MFMA of slot s-1, hence before the
// barrier that precedes the issue point.
// Swizzle (64-B rows, proven R3/R5): phys 8-bf16 slot = logical ^ ((row>>1)&3),
// applied on staging SOURCE k-offset and ds_read address; gload dest linear.

#define GEMM_PROLOGUE(AROWPTR_EXPR, BROW_STRIDE)                               \
  int tid = threadIdx.x;                                                       \
  int lane = tid & 63, wave = tid >> 6;                                        \
  int wm = wave >> 2, wn = wave & 3;                                           \
  int lr = lane & 15, g = lane >> 4;                                           \
  const bf16* aPtr[2]; const bf16* bPtr[2]; int ldsOff[2];                     \
  _Pragma("unroll")                                                            \
  for (int j = 0; j < 2; ++j) {                                                \
    int ci = j * 512 + tid;                                                    \
    int r = ci >> 2, sg = ci & 3;                                              \
    int ks = sg ^ ((r >> 1) & 3);                                              \
    aPtr[j] = (AROWPTR_EXPR) + ks * 8;                                         \
    bPtr[j] = Bbase + (size_t)r * (BROW_STRIDE) + ks * 8;                      \
    ldsOff[j] = j * 4096 + wave * 512;                                         \
  }                                                                            \
  int swz = (g ^ ((lr >> 1) & 3)) << 3;                                        \
  int aRd = (wm * 128 + lr) * 32 + swz;                                        \
  int bRd = (wn * 64 + lr) * 32 + swz;                                         \
  f32x4 acc[8][4];                                                             \
  _Pragma("unroll")                                                            \
  for (int m = 0; m < 8; ++m)                                                  \
    _Pragma("unroll")                                                          \
    for (int n = 0; n < 4; ++n) acc[m][n] = (f32x4){0.f, 0.f, 0.f, 0.f};

#define STAGE_A(sl) do {                                                       \
    _Pragma("unroll")                                                          \
    for (int j = 0; j < 2; ++j)                                                \
      gload16(aPtr[j] + (size_t)(sl) * 32, &Ab[(sl) & 3][ldsOff[j]]);          \
  } while (0)
#define STAGE_B(sl) do {                                                       \
    _Pragma("unroll")                                                          \
    for (int j = 0; j < 2; ++j)                                                \
      gload16(bPtr[j] + (size_t)(sl) * 32, &Bb[(sl) & 3][ldsOff[j]]);          \
  } while (0)

#define MFMA16(MB)                                                             \
  _Pragma("unroll")                                                            \
  for (int mm = 0; mm < 4; ++mm)                                               \
    _Pragma("unroll")                                                          \
    for (int nn = 0; nn < 4; ++nn)                                             \
      acc[(MB) + mm][nn] = __builtin_amdgcn_mfma_f32_16x16x32_bf16(            \
          af[mm], bfr[nn], acc[(MB) + mm][nn], 0, 0, 0);

#define GEMM_KLOOP(NT)                                                         \
  STAGE_A(0); STAGE_B(0); STAGE_A(1); STAGE_B(1); STAGE_A(2); STAGE_B(2);      \
  asm volatile("s_waitcnt vmcnt(8)" ::: "memory");                             \
  __builtin_amdgcn_sched_barrier(0);                                           \
  __builtin_amdgcn_s_barrier();                                                \
  __builtin_amdgcn_sched_barrier(0);                                           \
  _Pragma("unroll 1")                                                          \
  for (int s = 0; s < (NT); ++s) {                                             \
    const bf16* Asl = &Ab[s & 3][0];                                           \
    const bf16* Bsl = &Bb[s & 3][0];                                           \
    bf16x8 af[4], bfr[4];                                                      \
    /* ---- phase 0 ---- */                                                    \
    _Pragma("unroll")                                                          \
    for (int mm = 0; mm < 4; ++mm)                                             \
      af[mm] = *reinterpret_cast<const bf16x8*>(&Asl[aRd + mm * 512]);         \
    _Pragma("unroll")                                                          \
    for (int nn = 0; nn < 4; ++nn)                                             \
      bfr[nn] = *reinterpret_cast<const bf16x8*>(&Bsl[bRd + nn * 512]);        \
    if (s + 3 < (NT)) STAGE_A(s + 3);                                          \
    __builtin_amdgcn_sched_barrier(0);                                         \
    __builtin_amdgcn_s_barrier();                                              \
    asm volatile("s_waitcnt lgkmcnt(0)" ::: "memory");                         \
    __builtin_amdgcn_sched_barrier(0);                                         \
    __builtin_amdgcn_s_setprio(1);                                             \
    MFMA16(0)                                                                  \
    __builtin_amdgcn_s_setprio(0);                                             \
    __builtin_amdgcn_sched_barrier(0);                                         \
    __builtin_amdgcn_s_barrier();                                              \
    __builtin_amdgcn_sched_barrier(0);                                         \
    /* ---- phase 1 ---- */                                                    \
    _Pragma("unroll")                                                          \
    for (int mm = 0; mm < 4; ++mm)                                             \
      af[mm] = *reinterpret_cast<const bf16x8*>(&Asl[aRd + (mm + 4) * 512]);   \
    if (s + 3 < (NT)) STAGE_B(s + 3);                                          \
    if (s < (NT) - 3)       asm volatile("s_waitcnt vmcnt(8)" ::: "memory");   \
    else if (s == (NT) - 3) asm volatile("s_waitcnt vmcnt(4)" ::: "memory");   \
    else if (s == (NT) - 2) asm volatile("s_waitcnt vmcnt(0)" ::: "memory");   \
    __builtin_amdgcn_sched_barrier(0);                                         \
    __builtin_amdgcn_s_barrier();                                              \
    asm volatile("s_waitcnt lgkmcnt(0)" ::: "memory");                         \
    __builtin_amdgcn_sched_barrier(0);                                         \
    __builtin_amdgcn_s_setprio(1);                                             \
    MFMA16(4)                                                                  \
    __builtin_amdgcn_s_setprio(0);                                             \
    __builtin_amdgcn_sched_barrier(0);                                         \
    __builtin_amdgcn_s_barrier();                                              \
    __builtin_amdgcn_sched_barrier(0);                                         \
  }

// ---------------- grouped GEMM 1: h = gelu(x_gather @ w1^T) ----------------

__device__ __forceinline__ float gelu_tanh(float v) {
  float c = 0.7978845608028654f * (v + 0.044715f * v * v * v);
  c = fminf(fmaxf(c, -15.f), 15.f);
  float ex = __expf(2.f * c);
  float t = (ex - 1.f) / (ex + 1.f);
  return 0.5f * v * (1.f + t);
}

__global__ __launch_bounds__(512, 2) void gemm1_k(const bf16* __restrict__ xb,
                                                  const bf16* __restrict__ w1bT,
                                                  bf16* __restrict__ h,
                                                  const int* __restrict__ rowTok,
                                                  const int* __restrict__ padOff,
                                                  int tileStart, int rowStart) {
  __shared__ __attribute__((aligned(16))) bf16 Ab[4][8192];
  __shared__ __attribute__((aligned(16))) bf16 Bb[4][8192];
  const int nCT = FFN / 256;                       // 16 col tiles
  int wg = xcd_swz((int)blockIdx.x, (int)gridDim.x);
  int bt = tileStart + wg / nCT;
  int ct = wg % nCT;
  int r0 = bt * BM2;
  if (r0 >= padOff[NEXP]) return;
  int e = 0;
  while (padOff[e + 1] <= r0) ++e;
  const bf16* Bbase = w1bT + ((size_t)e * FFN + (size_t)ct * 256) * HIDDEN;

  GEMM_PROLOGUE(xb + (size_t)(rowTok[r0 + r] < 0 ? 0 : rowTok[r0 + r]) * HIDDEN,
                HIDDEN)
  GEMM_KLOOP(HIDDEN / 32)

  int colBase = ct * 256 + wn * 64 + lr;
  #pragma unroll
  for (int m = 0; m < 8; ++m) {
    #pragma unroll
    for (int i = 0; i < 4; ++i) {
      int t = r0 + wm * 128 + m * 16 + g * 4 + i;
      bf16* hp = h + (size_t)(t - rowStart) * FFN + colBase;
      #pragma unroll
      for (int n = 0; n < 4; ++n)
        hp[n * 16] = (bf16)gelu_tanh(acc[m][n][i]);
    }
  }
}

// ---------------- grouped GEMM 2: y = h @ w2^T (bf16 y, no atomics) ----------------

__global__ __launch_bounds__(512, 2) void gemm2_k(const bf16* __restrict__ h,
                                                  const bf16* __restrict__ w2bT,
                                                  bf16* __restrict__ y,
                                                  const int* __restrict__ padOff,
                                                  int tileStart, int rowStart) {
  __shared__ __attribute__((aligned(16))) bf16 Ab[4][8192];
  __shared__ __attribute__((aligned(16))) bf16 Bb[4][8192];
  const int nCT = HIDDEN / 256;                    // 4 col tiles
  int wg = xcd_swz((int)blockIdx.x, (int)gridDim.x);
  int bt = tileStart + wg / nCT;
  int ct = wg % nCT;
  int r0 = bt * BM2;
  if (r0 >= padOff[NEXP]) return;
  int e = 0;
  while (padOff[e + 1] <= r0) ++e;
  const bf16* Bbase = w2bT + ((size_t)e * HIDDEN + (size_t)ct * 256) * FFN;

  GEMM_PROLOGUE(h + (size_t)(r0 - rowStart + r) * FFN, FFN)
  GEMM_KLOOP(FFN / 32)

  int colBase = ct * 256 + wn * 64 + lr;
  #pragma unroll
  for (int m = 0; m < 8; ++m) {
    #pragma unroll
    for (int i = 0; i < 4; ++i) {
      int t = r0 + wm * 128 + m * 16 + g * 4 + i;
      bf16* yp = y + (size_t)t * HIDDEN + colBase;
      #pragma unroll
      for (int n = 0; n < 4; ++n)
        yp[n * 16] = (bf16)acc[m][n][i];
    }
  }
}

// ---------------- combine: out[n] = w0*y[r0] + w1*y[r1] ----------------

__global__ __launch_bounds__(256) void combine_k(const bf16* __restrict__ y,
                                                 const int* __restrict__ tokRow,
                                                 const float* __restrict__ rowW,
                                                 float* __restrict__ out) {
  int n = blockIdx.x;
  int c = threadIdx.x * 4;
  int r0 = tokRow[2 * n], r1 = tokRow[2 * n + 1];
  float w0 = rowW[r0], w1 = rowW[r1];
  bf16x4 a = *reinterpret_cast<const bf16x4*>(y + (size_t)r0 * HIDDEN + c);
  bf16x4 b = *reinterpret_cast<const bf16x4*>(y + (size_t)r1 * HIDDEN + c);
  float4 o = { w0 * (float)a[0] + w1 * (float)b[0], w0 * (float)a[1] + w1 * (float)b[1],
               w0 * (float)a[2] + w1 * (float)b[2], w0 * (float)a[3] + w1 * (float)b[3] };
  *reinterpret_cast<float4*>(out + (size_t)n * HIDDEN + c) = o;
}

// ---------------- host ----------------

extern "C" void kernel_launch(void* const* d_in, const int* in_sizes, int n_in,
                              void* d_out, int out_size, void* d_ws, size_t ws_size,
                              hipStream_t stream) {
  const float* x   = (const float*)d_in[0];
  const float* wrt = (const float*)d_in[1];
  const float* w1  = (const float*)d_in[2];
  const float* w2  = (const float*)d_in[3];
  float* out = (float*)d_out;

  char* p = (char*)d_ws;
  size_t off = 0;
  auto alloc = [&](size_t bytes) -> void* {
    void* r = p + off;
    off = (off + bytes + 255) & ~(size_t)255;
    return r;
  };

  int*    counts  = (int*)   alloc(NEXP * 4);
  int*    padOff  = (int*)   alloc((NEXP + 1) * 4);
  int*    cursor  = (int*)   alloc(NEXP * 4);
  int*    expIdx  = (int*)   alloc((size_t)N_TOKENS * 2 * 4);
  float*  expW    = (float*) alloc((size_t)N_TOKENS * 2 * 4);
  int*    rowTok  = (int*)   alloc((size_t)MAXR * 4);
  float*  rowW    = (float*) alloc((size_t)MAXR * 4);
  int*    tokRow  = (int*)   alloc((size_t)N_TOKENS * 2 * 4);
  double* logitsE = (double*)alloc((size_t)NEXP * N_TOKENS * 8);
  bf16*   xb      = (bf16*)  alloc((size_t)N_TOKENS * HIDDEN * 2);
  bf16*   w1bT    = (bf16*)  alloc((size_t)NEXP * FFN * HIDDEN * 2);
  bf16*   w2bT    = (bf16*)  alloc((size_t)NEXP * FFN * HIDDEN * 2);
  bf16*   y       = (bf16*)  alloc((size_t)MAXR * HIDDEN * 2);
  size_t fixed = off;
  bf16* h = (bf16*)(p + fixed);

  size_t tileB = (size_t)BM2 * FFN * 2;            // 2 MiB per 256-row tile of h
  size_t avail = (ws_size > fixed) ? (ws_size - fixed) : tileB;
  size_t fitSz = avail / tileB;
  int tilesFit = (int)((fitSz < (size_t)MAXTILES) ? fitSz : (size_t)MAXTILES);
  if (tilesFit < 1) tilesFit = 1;
  int nchunks = (MAXTILES + tilesFit - 1) / tilesFit;
  int tpc = (MAXTILES + nchunks - 1) / nchunks;

  hipMemsetAsync(counts, 0, NEXP * 4, stream);
  hipMemsetAsync(rowTok, 0xFF, (size_t)MAXR * 4, stream);

  convx_k<<<N_TOKENS * HIDDEN / 4 / 256, 256, 0, stream>>>(x, xb);
  transconv_k<<<dim3(FFN / 64, HIDDEN / 64, NEXP), dim3(256, 1, 1), 0, stream>>>(w1, w1bT, HIDDEN, FFN);
  transconv_k<<<dim3(HIDDEN / 64, FFN / 64, NEXP), dim3(256, 1, 1), 0, stream>>>(w2, w2bT, FFN, HIDDEN);
  logits_k<<<N_TOKENS / 32, 256, 0, stream>>>(x, wrt, logitsE);
  route_k<<<N_TOKENS / 256, 256, 0, stream>>>(logitsE, expIdx, expW, counts);
  offsets_k<<<1, 64, 0, stream>>>(counts, padOff, cursor);
  scatter_k<<<N_TOKENS / 256, 256, 0, stream>>>(expIdx, expW, padOff, cursor, rowTok, rowW, tokRow);

  for (int c = 0; c < nchunks; ++c) {
    int ts = c * tpc;
    int rs = ts * BM2;
    gemm1_k<<<tpc * (FFN / 256), 512, 0, stream>>>(xb, w1bT, h, rowTok, padOff, ts, rs);
    gemm2_k<<<tpc * (HIDDEN / 256), 512, 0, stream>>>(h, w2bT, y, padOff, ts, rs);
  }
  combine_k<<<N_TOKENS, 256, 0, stream>>>(y, tokRow, rowW, out);
}

// Round 7
// 943.064 us; speedup vs baseline: 1.2784x; 1.0862x over previous
//
#include <hip/hip_runtime.h>
#include <cstdint>
#include <cstddef>

#define N_TOKENS 16384
#define HIDDEN 1024
#define FFN 4096
#define NEXP 8
#define BM 128                        /* GEMM tile (M and N) */
#define BKS 32                        /* K slot */
#define MAXR (N_TOKENS*2 + NEXP*BM)   /* 33792 padded assignment rows */
#define MAXTILES (MAXR/BM)            /* 264 */

typedef __bf16 bf16;
typedef __attribute__((ext_vector_type(8))) __bf16 bf16x8;
typedef __attribute__((ext_vector_type(4))) __bf16 bf16x4;
typedef __attribute__((ext_vector_type(4))) float f32x4;

__device__ __forceinline__ void gload16(const void* g, void* l) {
  __builtin_amdgcn_global_load_lds((const __attribute__((address_space(1))) void*)g,
                                   (__attribute__((address_space(3))) void*)l, 16, 0, 0);
}

// bijective XCD swizzle (m204): contiguous wg chunk per XCD
__device__ __forceinline__ int xcd_swz(int orig, int nwg) {
  int q = nwg >> 3, r = nwg & 7;
  int xcd = orig & 7, idx = orig >> 3;
  int base = (xcd < r) ? xcd * (q + 1) : r * (q + 1) + (xcd - r) * q;
  return base + idx;
}

// ---------------- conversion kernels ----------------

__global__ __launch_bounds__(256) void convx_k(const float* __restrict__ x,
                                               bf16* __restrict__ xb) {
  int i = blockIdx.x * 256 + threadIdx.x;              // over float4s
  float4 v = reinterpret_cast<const float4*>(x)[i];
  bf16x4 o = { (bf16)v.x, (bf16)v.y, (bf16)v.z, (bf16)v.w };
  *reinterpret_cast<bf16x4*>(xb + (size_t)i * 4) = o;
}

// src [z][R][C] f32 -> dst [z][C][R] bf16  (transpose + convert), 64x64 tiles
__global__ __launch_bounds__(256) void transconv_k(const float* __restrict__ src,
                                                   bf16* __restrict__ dst,
                                                   int R, int C) {
  __shared__ float tile[64][65];
  int bx = blockIdx.x * 64;   // col base (C dim)
  int by = blockIdx.y * 64;   // row base (R dim)
  const float* s = src + (size_t)blockIdx.z * R * C;
  bf16* d = dst + (size_t)blockIdx.z * R * C;
  int tid = threadIdx.x;
  int tc = (tid & 15) * 4;    // col within tile (float4)
  int tr = tid >> 4;          // 0..15
  #pragma unroll
  for (int p = 0; p < 4; ++p) {
    int r = p * 16 + tr;
    float4 v = *reinterpret_cast<const float4*>(s + (size_t)(by + r) * C + bx + tc);
    tile[r][tc] = v.x; tile[r][tc + 1] = v.y; tile[r][tc + 2] = v.z; tile[r][tc + 3] = v.w;
  }
  __syncthreads();
  int wr = (tid & 15) * 4;    // row within tile (bf16x4)
  int wc = tid >> 4;
  #pragma unroll
  for (int p = 0; p < 4; ++p) {
    int c = p * 16 + wc;
    bf16x4 o = { (bf16)tile[wr][c], (bf16)tile[wr + 1][c],
                 (bf16)tile[wr + 2][c], (bf16)tile[wr + 3][c] };
    *reinterpret_cast<bf16x4*>(d + (size_t)(bx + c) * R + by + wr) = o;
  }
}

// ---------------- router: logits (f64, one thread per token,expert) ----------------

__global__ __launch_bounds__(256) void logits_k(const float* __restrict__ x,
                                                const float* __restrict__ wrt,
                                                double* __restrict__ logitsE) {
  __shared__ float wT[NEXP][HIDDEN + 1];
  int tid = threadIdx.x;
  for (int i = tid; i < HIDDEN * NEXP; i += 256) {
    int k = i >> 3, e = i & 7;
    wT[e][k] = wrt[i];
  }
  __syncthreads();
  int t = blockIdx.x * 32 + (tid >> 3);     // token
  int e = tid & 7;                          // expert
  int goff = ((tid >> 3) & 7) * 4;          // per-group k stagger (bank spread)
  const float* xr = x + (size_t)t * HIDDEN;
  double acc = 0.0;
  #pragma unroll 4
  for (int k = 0; k < HIDDEN; k += 4) {
    int kk = (k + goff) & (HIDDEN - 1);
    float4 v = *reinterpret_cast<const float4*>(xr + kk);   // broadcast across 8 lanes
    acc += (double)v.x * (double)wT[e][kk];
    acc += (double)v.y * (double)wT[e][kk + 1];
    acc += (double)v.z * (double)wT[e][kk + 2];
    acc += (double)v.w * (double)wT[e][kk + 3];
  }
  logitsE[(size_t)e * N_TOKENS + t] = acc;
}

// ---------------- router: top-2 + weights + histogram ----------------

__global__ __launch_bounds__(256) void route_k(const double* __restrict__ logitsE,
                                               int* __restrict__ expIdx,
                                               float* __restrict__ expW,
                                               int* __restrict__ counts) {
  __shared__ int lcnt[NEXP];
  int tid = threadIdx.x;
  if (tid < NEXP) lcnt[tid] = 0;
  __syncthreads();
  int n = blockIdx.x * 256 + tid;
  double lg[NEXP];
  #pragma unroll
  for (int e = 0; e < NEXP; ++e) lg[e] = logitsE[(size_t)e * N_TOKENS + n];
  int e1 = 0;
  #pragma unroll
  for (int e = 1; e < NEXP; ++e) if (lg[e] > lg[e1]) e1 = e;
  int e2 = (e1 == 0) ? 1 : 0;
  #pragma unroll
  for (int e = 0; e < NEXP; ++e)
    if (e != e1 && e != e2 && lg[e] > lg[e2]) e2 = e;
  double d = lg[e2] - lg[e1];                                      // <= 0
  float w1v = (float)(1.0 / (1.0 + exp(d)));
  expIdx[2 * n]     = e1; expIdx[2 * n + 1] = e2;
  expW[2 * n]       = w1v; expW[2 * n + 1]  = 1.0f - w1v;
  atomicAdd(&lcnt[e1], 1);
  atomicAdd(&lcnt[e2], 1);
  __syncthreads();
  if (tid < NEXP) atomicAdd(&counts[tid], lcnt[tid]);
}

// ---------------- segment offsets + scatter ----------------

__global__ void offsets_k(const int* __restrict__ counts,
                          int* __restrict__ padOff, int* __restrict__ cursor) {
  if (threadIdx.x == 0) {
    int o = 0;
    for (int e = 0; e < NEXP; ++e) {
      padOff[e] = o;
      o += ((counts[e] + BM - 1) / BM) * BM;           // 128-aligned segments
    }
    padOff[NEXP] = o;
  }
  if (threadIdx.x < NEXP) cursor[threadIdx.x] = 0;
}

__global__ __launch_bounds__(256) void scatter_k(const int* __restrict__ expIdx,
                                                 const float* __restrict__ expW,
                                                 const int* __restrict__ padOff,
                                                 int* __restrict__ cursor,
                                                 int* __restrict__ rowTok,
                                                 float* __restrict__ rowW,
                                                 int* __restrict__ tokRow) {
  __shared__ int lcnt[NEXP], lbase[NEXP];
  int tid = threadIdx.x;
  if (tid < NEXP) lcnt[tid] = 0;
  __syncthreads();
  int n = blockIdx.x * 256 + tid;
  int e0 = expIdx[2 * n], e1 = expIdx[2 * n + 1];
  float w0 = expW[2 * n], w1 = expW[2 * n + 1];
  int p0 = atomicAdd(&lcnt[e0], 1);
  int p1 = atomicAdd(&lcnt[e1], 1);
  __syncthreads();
  if (tid < NEXP) lbase[tid] = atomicAdd(&cursor[tid], lcnt[tid]);
  __syncthreads();
  int r0 = padOff[e0] + lbase[e0] + p0;
  int r1 = padOff[e1] + lbase[e1] + p1;
  rowTok[r0] = n;  rowW[r0] = w0;  tokRow[2 * n]     = r0;
  rowTok[r1] = n;  rowW[r1] = w1;  tokRow[2 * n + 1] = r1;
}

// ---------------- 128^2 grouped GEMM core: depth-3 rotation + 3 blocks/CU ----------------
// 256 thr = 4 waves (2M x 2N); per-wave C = 64x64 = acc[4][4] 16x16 frags.
// LDS: 3 slot-buffers x (A 128x32 + B 128x32) bf16 = 48 KB -> 3 blocks/CU.
// Per K-step s (read buf, stage slot s+2 into the buffer freed at step s-1):
//   stage(s+2) ; vmcnt(8) [exact: 4 loads/slot, 2 slots in flight ->
//   issued=4(s+3), completed >= 4(s+1) = slot s landed] ; barrier ;
//   ds_read 8 x b128 ; 16 MFMA (compiler lgkmcnt) ; barrier.
// Tail: vmcnt(4) at s=NT-2, vmcnt(0) at s=NT-1.
// Swizzle (64-B rows, 0-conflict proven R3/R5): phys 8-bf16 octet =
// logical ^ ((row>>1)&3); applied on staging SOURCE and ds_read; LDS linear.

__device__ __forceinline__ float gelu_tanh(float v) {
  float c = 0.7978845608028654f * (v + 0.044715f * v * v * v);
  c = fminf(fmaxf(c, -15.f), 15.f);
  float ex = __expf(2.f * c);
  float t = (ex - 1.f) / (ex + 1.f);
  return 0.5f * v * (1.f + t);
}

__global__ __launch_bounds__(256, 3) void gemm1_k(const bf16* __restrict__ xb,
                                                  const bf16* __restrict__ w1bT,
                                                  bf16* __restrict__ h,
                                                  const int* __restrict__ rowTok,
                                                  const int* __restrict__ padOff,
                                                  int tileStart, int rowStart) {
  __shared__ __attribute__((aligned(16))) bf16 Ab[3][BM * BKS];
  __shared__ __attribute__((aligned(16))) bf16 Bb[3][BM * BKS];
  const int nCT = FFN / 128;                       // 32 col tiles
  int wg = xcd_swz((int)blockIdx.x, (int)gridDim.x);
  int bt = tileStart + wg / nCT;
  int ct = wg % nCT;
  int r0 = bt * BM;
  if (r0 >= padOff[NEXP]) return;
  int e = 0;
  while (padOff[e + 1] <= r0) ++e;
  const bf16* Bbase = w1bT + ((size_t)e * FFN + (size_t)ct * 128) * HIDDEN;

  int tid = threadIdx.x;
  int lane = tid & 63, wave = tid >> 6;
  const bf16* aPtr[2]; const bf16* bPtr[2]; int ldsOff[2];
  #pragma unroll
  for (int j = 0; j < 2; ++j) {
    int ci = j * 256 + tid;
    int r = ci >> 2, sg = ci & 3;
    int ks = sg ^ ((r >> 1) & 3);
    int tok = rowTok[r0 + r]; if (tok < 0) tok = 0;
    aPtr[j] = xb + (size_t)tok * HIDDEN + ks * 8;
    bPtr[j] = Bbase + (size_t)r * HIDDEN + ks * 8;
    ldsOff[j] = ci * 8;
  }
  int lr = lane & 15, g = lane >> 4;
  int wm = wave >> 1, wn = wave & 1;
  int aOff[4], bOff[4];
  #pragma unroll
  for (int m = 0; m < 4; ++m) { int r = wm * 64 + m * 16 + lr; aOff[m] = r * BKS + ((g ^ ((r >> 1) & 3)) << 3); }
  #pragma unroll
  for (int n = 0; n < 4; ++n) { int r = wn * 64 + n * 16 + lr; bOff[n] = r * BKS + ((g ^ ((r >> 1) & 3)) << 3); }

  f32x4 acc[4][4];
  #pragma unroll
  for (int m = 0; m < 4; ++m)
    #pragma unroll
    for (int n = 0; n < 4; ++n) acc[m][n] = (f32x4){0.f, 0.f, 0.f, 0.f};

  const int NT = HIDDEN / BKS;                     // 32
  auto stage = [&](int sl, int b) {
    #pragma unroll
    for (int j = 0; j < 2; ++j) gload16(aPtr[j] + (size_t)sl * BKS, &Ab[b][ldsOff[j]]);
    #pragma unroll
    for (int j = 0; j < 2; ++j) gload16(bPtr[j] + (size_t)sl * BKS, &Bb[b][ldsOff[j]]);
  };
  stage(0, 0); stage(1, 1);
  int buf = 0, sbuf = 2;
  #pragma unroll 1
  for (int s = 0; s < NT; ++s) {
    if (s + 2 < NT) stage(s + 2, sbuf);
    if (s < NT - 2)       asm volatile("s_waitcnt vmcnt(8)" ::: "memory");
    else if (s == NT - 2) asm volatile("s_waitcnt vmcnt(4)" ::: "memory");
    else                  asm volatile("s_waitcnt vmcnt(0)" ::: "memory");
    __builtin_amdgcn_sched_barrier(0);
    __builtin_amdgcn_s_barrier();
    __builtin_amdgcn_sched_barrier(0);
    bf16x8 af[4], bfr[4];
    #pragma unroll
    for (int m = 0; m < 4; ++m) af[m] = *reinterpret_cast<const bf16x8*>(&Ab[buf][aOff[m]]);
    #pragma unroll
    for (int n = 0; n < 4; ++n) bfr[n] = *reinterpret_cast<const bf16x8*>(&Bb[buf][bOff[n]]);
    __builtin_amdgcn_s_setprio(1);
    #pragma unroll
    for (int m = 0; m < 4; ++m)
      #pragma unroll
      for (int n = 0; n < 4; ++n)
        acc[m][n] = __builtin_amdgcn_mfma_f32_16x16x32_bf16(af[m], bfr[n], acc[m][n], 0, 0, 0);
    __builtin_amdgcn_s_setprio(0);
    __builtin_amdgcn_sched_barrier(0);
    __builtin_amdgcn_s_barrier();
    __builtin_amdgcn_sched_barrier(0);
    buf = (buf == 2) ? 0 : buf + 1;
    sbuf = (sbuf == 2) ? 0 : sbuf + 1;
  }

  int colBase = ct * 128 + wn * 64 + lr;
  #pragma unroll
  for (int m = 0; m < 4; ++m) {
    #pragma unroll
    for (int i = 0; i < 4; ++i) {
      int t = r0 + wm * 64 + m * 16 + g * 4 + i;
      bf16* hp = h + (size_t)(t - rowStart) * FFN + colBase;
      #pragma unroll
      for (int n = 0; n < 4; ++n)
        hp[n * 16] = (bf16)gelu_tanh(acc[m][n][i]);
    }
  }
}

__global__ __launch_bounds__(256, 3) void gemm2_k(const bf16* __restrict__ h,
                                                  const bf16* __restrict__ w2bT,
                                                  bf16* __restrict__ y,
                                                  const int* __restrict__ padOff,
                                                  int tileStart, int rowStart) {
  __shared__ __attribute__((aligned(16))) bf16 Ab[3][BM * BKS];
  __shared__ __attribute__((aligned(16))) bf16 Bb[3][BM * BKS];
  const int nCT = HIDDEN / 128;                    // 8 col tiles
  int wg = xcd_swz((int)blockIdx.x, (int)gridDim.x);
  int bt = tileStart + wg / nCT;
  int ct = wg % nCT;
  int r0 = bt * BM;
  if (r0 >= padOff[NEXP]) return;
  int e = 0;
  while (padOff[e + 1] <= r0) ++e;
  const bf16* Bbase = w2bT + ((size_t)e * HIDDEN + (size_t)ct * 128) * FFN;
  const bf16* Arow = h + (size_t)(r0 - rowStart) * FFN;

  int tid = threadIdx.x;
  int lane = tid & 63, wave = tid >> 6;
  const bf16* aPtr[2]; const bf16* bPtr[2]; int ldsOff[2];
  #pragma unroll
  for (int j = 0; j < 2; ++j) {
    int ci = j * 256 + tid;
    int r = ci >> 2, sg = ci & 3;
    int ks = sg ^ ((r >> 1) & 3);
    aPtr[j] = Arow + (size_t)r * FFN + ks * 8;
    bPtr[j] = Bbase + (size_t)r * FFN + ks * 8;
    ldsOff[j] = ci * 8;
  }
  int lr = lane & 15, g = lane >> 4;
  int wm = wave >> 1, wn = wave & 1;
  int aOff[4], bOff[4];
  #pragma unroll
  for (int m = 0; m < 4; ++m) { int r = wm * 64 + m * 16 + lr; aOff[m] = r * BKS + ((g ^ ((r >> 1) & 3)) << 3); }
  #pragma unroll
  for (int n = 0; n < 4; ++n) { int r = wn * 64 + n * 16 + lr; bOff[n] = r * BKS + ((g ^ ((r >> 1) & 3)) << 3); }

  f32x4 acc[4][4];
  #pragma unroll
  for (int m = 0; m < 4; ++m)
    #pragma unroll
    for (int n = 0; n < 4; ++n) acc[m][n] = (f32x4){0.f, 0.f, 0.f, 0.f};

  const int NT = FFN / BKS;                        // 128
  auto stage = [&](int sl, int b) {
    #pragma unroll
    for (int j = 0; j < 2; ++j) gload16(aPtr[j] + (size_t)sl * BKS, &Ab[b][ldsOff[j]]);
    #pragma unroll
    for (int j = 0; j < 2; ++j) gload16(bPtr[j] + (size_t)sl * BKS, &Bb[b][ldsOff[j]]);
  };
  stage(0, 0); stage(1, 1);
  int buf = 0, sbuf = 2;
  #pragma unroll 1
  for (int s = 0; s < NT; ++s) {
    if (s + 2 < NT) stage(s + 2, sbuf);
    if (s < NT - 2)       asm volatile("s_waitcnt vmcnt(8)" ::: "memory");
    else if (s == NT - 2) asm volatile("s_waitcnt vmcnt(4)" ::: "memory");
    else                  asm volatile("s_waitcnt vmcnt(0)" ::: "memory");
    __builtin_amdgcn_sched_barrier(0);
    __builtin_amdgcn_s_barrier();
    __builtin_amdgcn_sched_barrier(0);
    bf16x8 af[4], bfr[4];
    #pragma unroll
    for (int m = 0; m < 4; ++m) af[m] = *reinterpret_cast<const bf16x8*>(&Ab[buf][aOff[m]]);
    #pragma unroll
    for (int n = 0; n < 4; ++n) bfr[n] = *reinterpret_cast<const bf16x8*>(&Bb[buf][bOff[n]]);
    __builtin_amdgcn_s_setprio(1);
    #pragma unroll
    for (int m = 0; m < 4; ++m)
      #pragma unroll
      for (int n = 0; n < 4; ++n)
        acc[m][n] = __builtin_amdgcn_mfma_f32_16x16x32_bf16(af[m], bfr[n], acc[m][n], 0, 0, 0);
    __builtin_amdgcn_s_setprio(0);
    __builtin_amdgcn_sched_barrier(0);
    __builtin_amdgcn_s_barrier();
    __builtin_amdgcn_sched_barrier(0);
    buf = (buf == 2) ? 0 : buf + 1;
    sbuf = (sbuf == 2) ? 0 : sbuf + 1;
  }

  int colBase = ct * 128 + wn * 64 + lr;
  #pragma unroll
  for (int m = 0; m < 4; ++m) {
    #pragma unroll
    for (int i = 0; i < 4; ++i) {
      int t = r0 + wm * 64 + m * 16 + g * 4 + i;
      bf16* yp = y + (size_t)t * HIDDEN + colBase;
      #pragma unroll
      for (int n = 0; n < 4; ++n)
        yp[n * 16] = (bf16)acc[m][n][i];
    }
  }
}

// ---------------- combine: out[n] = w0*y[r0] + w1*y[r1] ----------------

__global__ __launch_bounds__(256) void combine_k(const bf16* __restrict__ y,
                                                 const int* __restrict__ tokRow,
                                                 const float* __restrict__ rowW,
                                                 float* __restrict__ out) {
  int n = blockIdx.x;
  int c = threadIdx.x * 4;
  int r0 = tokRow[2 * n], r1 = tokRow[2 * n + 1];
  float w0 = rowW[r0], w1 = rowW[r1];
  bf16x4 a = *reinterpret_cast<const bf16x4*>(y + (size_t)r0 * HIDDEN + c);
  bf16x4 b = *reinterpret_cast<const bf16x4*>(y + (size_t)r1 * HIDDEN + c);
  float4 o = { w0 * (float)a[0] + w1 * (float)b[0], w0 * (float)a[1] + w1 * (float)b[1],
               w0 * (float)a[2] + w1 * (float)b[2], w0 * (float)a[3] + w1 * (float)b[3] };
  *reinterpret_cast<float4*>(out + (size_t)n * HIDDEN + c) = o;
}

// ---------------- host ----------------

extern "C" void kernel_launch(void* const* d_in, const int* in_sizes, int n_in,
                              void* d_out, int out_size, void* d_ws, size_t ws_size,
                              hipStream_t stream) {
  const float* x   = (const float*)d_in[0];
  const float* wrt = (const float*)d_in[1];
  const float* w1  = (const float*)d_in[2];
  const float* w2  = (const float*)d_in[3];
  float* out = (float*)d_out;

  char* p = (char*)d_ws;
  size_t off = 0;
  auto alloc = [&](size_t bytes) -> void* {
    void* r = p + off;
    off = (off + bytes + 255) & ~(size_t)255;
    return r;
  };

  int*    counts  = (int*)   alloc(NEXP * 4);
  int*    padOff  = (int*)   alloc((NEXP + 1) * 4);
  int*    cursor  = (int*)   alloc(NEXP * 4);
  int*    expIdx  = (int*)   alloc((size_t)N_TOKENS * 2 * 4);
  float*  expW    = (float*) alloc((size_t)N_TOKENS * 2 * 4);
  int*    rowTok  = (int*)   alloc((size_t)MAXR * 4);
  float*  rowW    = (float*) alloc((size_t)MAXR * 4);
  int*    tokRow  = (int*)   alloc((size_t)N_TOKENS * 2 * 4);
  double* logitsE = (double*)alloc((size_t)NEXP * N_TOKENS * 8);
  bf16*   xb      = (bf16*)  alloc((size_t)N_TOKENS * HIDDEN * 2);
  bf16*   w1bT    = (bf16*)  alloc((size_t)NEXP * FFN * HIDDEN * 2);
  bf16*   w2bT    = (bf16*)  alloc((size_t)NEXP * FFN * HIDDEN * 2);
  bf16*   y       = (bf16*)  alloc((size_t)MAXR * HIDDEN * 2);
  size_t fixed = off;
  bf16* h = (bf16*)(p + fixed);

  size_t tileB = (size_t)BM * FFN * 2;             // 1 MiB per 128-row tile of h
  size_t avail = (ws_size > fixed) ? (ws_size - fixed) : tileB;
  size_t fitSz = avail / tileB;
  int tilesFit = (int)((fitSz < (size_t)MAXTILES) ? fitSz : (size_t)MAXTILES);
  if (tilesFit < 1) tilesFit = 1;
  int nchunks = (MAXTILES + tilesFit - 1) / tilesFit;
  int tpc = (MAXTILES + nchunks - 1) / nchunks;

  hipMemsetAsync(counts, 0, NEXP * 4, stream);
  hipMemsetAsync(rowTok, 0xFF, (size_t)MAXR * 4, stream);

  convx_k<<<N_TOKENS * HIDDEN / 4 / 256, 256, 0, stream>>>(x, xb);
  transconv_k<<<dim3(FFN / 64, HIDDEN / 64, NEXP), dim3(256, 1, 1), 0, stream>>>(w1, w1bT, HIDDEN, FFN);
  transconv_k<<<dim3(HIDDEN / 64, FFN / 64, NEXP), dim3(256, 1, 1), 0, stream>>>(w2, w2bT, FFN, HIDDEN);
  logits_k<<<N_TOKENS / 32, 256, 0, stream>>>(x, wrt, logitsE);
  route_k<<<N_TOKENS / 256, 256, 0, stream>>>(logitsE, expIdx, expW, counts);
  offsets_k<<<1, 64, 0, stream>>>(counts, padOff, cursor);
  scatter_k<<<N_TOKENS / 256, 256, 0, stream>>>(expIdx, expW, padOff, cursor, rowTok, rowW, tokRow);

  for (int c = 0; c < nchunks; ++c) {
    int ts = c * tpc;
    int rs = ts * BM;
    gemm1_k<<<tpc * (FFN / 128), 256, 0, stream>>>(xb, w1bT, h, rowTok, padOff, ts, rs);
    gemm2_k<<<tpc * (HIDDEN / 128), 256, 0, stream>>>(h, w2bT, y, padOff, ts, rs);
  }
  combine_k<<<N_TOKENS, 256, 0, stream>>>(y, tokRow, rowW, out);
}